// Round 11
// baseline (87.908 us; speedup 1.0000x reference)
//
#include <hip/hip_runtime.h>

// Sinkhorn on 8192 independent 64x64 f32 matrices.
// R10 structure: 256-thread blocks = 4 waves = TWO matrices, each on its
// own 2-wave pair (32 RL + 32 FMA per matvec per wave, one LDS exchange,
// one barrier). NEW: __launch_bounds__(256, 4) — force the allocator to
// fit each wave in <=128 unified VGPR+AGPR regs. Evidence: residency
// tracks register budget, not block size (VGPR 28-32 -> 24 waves/CU,
// VGPR 52-64 (+hidden AGPRs for the 64 K floats) -> 12 waves/CU). Data
// is 64 floats + ~30 work regs, so 128 fits without spilling; 4 blocks/CU
// -> 16 waves/CU (+33% TLP to hide the serial LDS-roundtrip latency).
// Wave pair p (matrix 2*blockIdx+p), wave half h:
//   rK[k] = A[lane][32h+k]  (row `lane`, column-half)  -> partial K*v
//   cK[i] = A[32h+i][lane]  (col `lane`, row-half)     -> partial K^T*u
// u/v stored ROTATED (lane l holds index (l+32h)&63) so readlane indices
// are literals 0..31.

static constexpr int   kIters = 20;
static constexpr float kEps   = 1e-6f;

__device__ __forceinline__ float RLf(float x, int l) {
    return __int_as_float(__builtin_amdgcn_readlane(__float_as_int(x), l));
}

__global__ __launch_bounds__(256, 4) void sinkhorn64_2m4(const float* __restrict__ in,
                                                         float* __restrict__ out) {
    __shared__ float xb0[2][2][64];   // [matrix-pair][half][lane]
    __shared__ float xb1[2][2][64];
    const int tid  = threadIdx.x;
    const int wid  = tid >> 6;
    const int p    = wid >> 1;               // which matrix in this block
    const int h    = wid & 1;                // which half this wave owns
    const int lane = tid & 63;
    const int c    = (lane + 32 * h) & 63;   // rotated index (self-inverse)
    const long m   = (long)blockIdx.x * 2 + p;   // matrix 0..8191
    const float* __restrict__ A = in  + m * 4096;
    float* __restrict__ O       = out + m * 4096;

    // cK[i] = A[32h+i][lane]  (32 coalesced 256B loads)
    float cK[32];
#pragma unroll
    for (int i = 0; i < 32; ++i) cK[i] = A[((32 * h + i) << 6) + lane];

    // rK[k] = A[lane][32h+k]  (8 x float4 per lane; lines hot from cK pass)
    float rK[32];
#pragma unroll
    for (int k4 = 0; k4 < 8; ++k4) {
        const float4 f = *reinterpret_cast<const float4*>(A + (lane << 6) + 32 * h + (k4 << 2));
        rK[4 * k4 + 0] = f.x; rK[4 * k4 + 1] = f.y;
        rK[4 * k4 + 2] = f.z; rK[4 * k4 + 3] = f.w;
    }

    // Row max: own-half partial, exchange, combine (plain and rotated).
    float pm = rK[0];
#pragma unroll
    for (int k = 1; k < 32; ++k) pm = fmaxf(pm, rK[k]);
    xb0[p][h][lane] = pm;
    __syncthreads();
    const float mx  = fmaxf(pm, xb0[p][1 - h][lane]);      // max of row `lane`
    const float mxr = fmaxf(xb0[p][0][c], xb0[p][1][c]);   // max of row `c`

#pragma unroll
    for (int k = 0; k < 32; ++k) rK[k] = __expf(rK[k] - mx);
#pragma unroll
    for (int i = 0; i < 32; ++i) cK[i] = __expf(cK[i] - RLf(mxr, i));

    // Rotated scaling vectors: lane holds u_c, v_c.
    float ur = 1.0f, vr = 1.0f;

#pragma unroll 1
    for (int it = 0; it < kIters; ++it) {
        // partial (K v)_{row=lane} over own columns; v[32h+k] = lane k of vr
        float a0 = 0.f, a1 = 0.f, a2 = 0.f, a3 = 0.f;
#pragma unroll
        for (int k = 0; k < 32; k += 4) {
            a0 = fmaf(RLf(vr, k + 0), rK[k + 0], a0);
            a1 = fmaf(RLf(vr, k + 1), rK[k + 1], a1);
            a2 = fmaf(RLf(vr, k + 2), rK[k + 2], a2);
            a3 = fmaf(RLf(vr, k + 3), rK[k + 3], a3);
        }
        xb1[p][h][lane] = (a0 + a1) + (a2 + a3);
        __syncthreads();
        const float w = xb1[p][0][c] + xb1[p][1][c];          // w for row c
        ur = ur * __builtin_amdgcn_rcpf(fmaf(ur, w, kEps));

        // partial (K^T u)_{col=lane} over own rows; u[32h+i] = lane i of ur
        float b0 = 0.f, b1 = 0.f, b2 = 0.f, b3 = 0.f;
#pragma unroll
        for (int i = 0; i < 32; i += 4) {
            b0 = fmaf(RLf(ur, i + 0), cK[i + 0], b0);
            b1 = fmaf(RLf(ur, i + 1), cK[i + 1], b1);
            b2 = fmaf(RLf(ur, i + 2), cK[i + 2], b2);
            b3 = fmaf(RLf(ur, i + 3), cK[i + 3], b3);
        }
        xb0[p][h][lane] = (b0 + b1) + (b2 + b3);
        __syncthreads();
        const float t = xb0[p][0][c] + xb0[p][1][c];          // t for col c
        vr = vr * __builtin_amdgcn_rcpf(fmaf(vr, t, kEps));
    }

    // Unrotate v: wave h=0 of this pair holds identity layout.
    xb1[p][h][lane] = vr;
    __syncthreads();
    const float vfin = xb1[p][0][lane];

    // O[32h+i][lane] = u_{32h+i} * K[32h+i][lane] * v_lane  (coalesced)
#pragma unroll
    for (int i = 0; i < 32; ++i) {
        O[((32 * h + i) << 6) + lane] = RLf(ur, i) * cK[i] * vfin;
    }
}

extern "C" void kernel_launch(void* const* d_in, const int* in_sizes, int n_in,
                              void* d_out, int out_size, void* d_ws, size_t ws_size,
                              hipStream_t stream) {
    const float* in = (const float*)d_in[0];
    float* out      = (float*)d_out;
    // 8192 matrices, 2 matrices per 256-thread (4-wave) block.
    sinkhorn64_2m4<<<4096, 256, 0, stream>>>(in, out);
}